// Round 1
// baseline (550.164 us; speedup 1.0000x reference)
//
#include <hip/hip_runtime.h>

#define B_ 32
#define N_ 17
#define C_ 256
#define H_ 96
#define W_ 72
#define M_ (B_*N_)   // 544

// ---------------------------------------------------------------------------
// Kernel 1: gaussian 5x5 pooling at keypoint locations.
// One block per (b,n) keypoint, one thread per channel.
// ---------------------------------------------------------------------------
__global__ void gpool_kernel(const float* __restrict__ fmap,
                             const float* __restrict__ kpts,
                             float* __restrict__ kpt_out) {
  const int m = blockIdx.x;          // b*17 + n
  const int b = m / N_;
  const int c = threadIdx.x;         // channel
  const float kx = kpts[m*2+0] * ((float)W_ / 288.0f);   // 0.25
  const float ky = kpts[m*2+1] * ((float)H_ / 384.0f);   // 0.25
  int xi = (int)kx; xi = min(max(xi, 2), W_-3);
  int yi = (int)ky; yi = min(max(yi, 2), H_-3);
  // separable normalized gaussian, sigma=2: exp(-d^2/8)/S
  const float e1 = 0.8824969025845955f;   // exp(-1/8)
  const float e4 = 0.6065306597126334f;   // exp(-4/8)
  const float S  = 1.0f + 2.0f*e1 + 2.0f*e4;
  const float w1d[5] = { e4/S, e1/S, 1.0f/S, e1/S, e4/S };
  const float* base = fmap + ((size_t)(b*C_ + c)*H_ + (yi-2))*W_ + (xi-2);
  float acc = 0.f;
  #pragma unroll
  for (int dy = 0; dy < 5; ++dy) {
    const float* row = base + dy*W_;
    float rs = 0.f;
    #pragma unroll
    for (int dx = 0; dx < 5; ++dx) rs = fmaf(row[dx], w1d[dx], rs);
    acc = fmaf(rs, w1d[dy], acc);
  }
  kpt_out[m*C_ + c] = acc;
}

// ---------------------------------------------------------------------------
// Kernel 2: per-row projections: Q,K,V (+bias), gate logits, P1 partial.
// 8 rows per block to amortize weight reads; 256 threads (one per out col).
// ---------------------------------------------------------------------------
__global__ void prep_kernel(const float* __restrict__ X, int nrows,
    const float* __restrict__ Wq, const float* __restrict__ bq,
    const float* __restrict__ Wk, const float* __restrict__ bk,
    const float* __restrict__ Wv, const float* __restrict__ bv,
    const float* __restrict__ Wg, const float* __restrict__ bg,
    const float* __restrict__ P1part,
    float* __restrict__ Q, float* __restrict__ Ko, float* __restrict__ V,
    float* __restrict__ G, float* __restrict__ P1out) {
  __shared__ float xs[8][C_];
  const int r0 = blockIdx.x * 8;
  const int c  = threadIdx.x;
  #pragma unroll
  for (int r = 0; r < 8; ++r)
    xs[r][c] = (r0 + r < nrows) ? X[(r0+r)*C_ + c] : 0.f;
  __syncthreads();

  const float* Ws[4]   = { Wq, Wk, Wv, P1part };
  const float* bsv[4]  = { bq, bk, bv, nullptr };
  float*       outs[4] = { Q, Ko, V, P1out };
  #pragma unroll
  for (int mtx = 0; mtx < 4; ++mtx) {
    const float* Wp = Ws[mtx];
    float bias = bsv[mtx] ? bsv[mtx][c] : 0.f;
    float acc[8];
    #pragma unroll
    for (int r = 0; r < 8; ++r) acc[r] = bias;
    for (int k = 0; k < C_; ++k) {
      float w = Wp[k*C_ + c];
      #pragma unroll
      for (int r = 0; r < 8; ++r) acc[r] = fmaf(xs[r][k], w, acc[r]);
    }
    float* op = outs[mtx];
    #pragma unroll
    for (int r = 0; r < 8; ++r)
      if (r0 + r < nrows) op[(r0+r)*C_ + c] = acc[r];
  }
  // gate logits: 8 rows x 8 heads = 64 threads
  if (c < 64) {
    int r = c >> 3, hh = c & 7;
    if (r0 + r < nrows) {
      float acc = bg[hh];
      for (int k = 0; k < C_; ++k) acc = fmaf(xs[r][k], Wg[k*8 + hh], acc);
      G[(r0+r)*8 + hh] = acc;
    }
  }
}

// ---------------------------------------------------------------------------
// Kernel 3: per-keypoint S=2 gated attention (mean over S) + LayerNorm+ReLU.
// One block per keypoint m, 256 threads (thread c -> head c>>5, lane c&31).
// ---------------------------------------------------------------------------
__global__ void attn_ln_kernel(
    const float* __restrict__ Qk, const float* __restrict__ Kk,
    const float* __restrict__ Vk, const float* __restrict__ Gk,
    const float* __restrict__ Qm, const float* __restrict__ Km,
    const float* __restrict__ Vm, const float* __restrict__ Gm,
    const float* __restrict__ P1k, const float* __restrict__ P1m,
    const float* __restrict__ P1b,
    const float* __restrict__ ln_g, const float* __restrict__ ln_b,
    float* __restrict__ Ymean, float* __restrict__ Hout) {
  const int m = blockIdx.x;
  const int n = m % N_;
  const int c = threadIdx.x;
  const int h = c >> 5;
  const float q0 = Qk[m*C_+c], k0 = Kk[m*C_+c], v0 = Vk[m*C_+c];
  const float q1 = Qm[n*C_+c], k1 = Km[n*C_+c], v1 = Vm[n*C_+c];
  float s00 = q0*k0, s01 = q0*k1, s10 = q1*k0, s11 = q1*k1;
  // butterfly sum within each 32-lane head group (masks <32 never cross)
  #pragma unroll
  for (int off = 16; off >= 1; off >>= 1) {
    s00 += __shfl_xor(s00, off);
    s01 += __shfl_xor(s01, off);
    s10 += __shfl_xor(s10, off);
    s11 += __shfl_xor(s11, off);
  }
  const float scale = 0.17677669529663687f;  // 1/sqrt(32)
  s00 *= scale; s01 *= scale; s10 *= scale; s11 *= scale;
  float mx0 = fmaxf(s00, s01), mx1 = fmaxf(s10, s11);
  float e00 = __expf(s00-mx0), e01 = __expf(s01-mx0);
  float e10 = __expf(s10-mx1), e11 = __expf(s11-mx1);
  float i0 = 1.f/(e00+e01), i1 = 1.f/(e10+e11);
  float g0 = 1.f/(1.f + __expf(-Gk[m*8+h]));
  float g1 = 1.f/(1.f + __expf(-Gm[n*8+h]));
  float y0 = (e00*i0*v0 + e01*i0*v1) * g0;
  float y1 = (e10*i1*v0 + e11*i1*v1) * g1;
  Ymean[m*C_+c] = 0.5f*(y0 + y1);

  // LayerNorm(P1k + P1m + P1b) -> ReLU
  float p = P1k[m*C_+c] + P1m[n*C_+c] + P1b[c];
  float s = p, s2 = p*p;
  #pragma unroll
  for (int off = 32; off >= 1; off >>= 1) {  // full 64-lane wave reduce
    s  += __shfl_xor(s, off);
    s2 += __shfl_xor(s2, off);
  }
  __shared__ float red[8];
  const int wv = c >> 6, ln = c & 63;
  if (ln == 0) { red[wv] = s; red[4+wv] = s2; }
  __syncthreads();
  float tot  = red[0]+red[1]+red[2]+red[3];
  float tot2 = red[4]+red[5]+red[6]+red[7];
  float mu   = tot * (1.f/256.f);
  float var  = tot2 * (1.f/256.f) - mu*mu;
  float rstd = rsqrtf(var + 1e-5f);
  float hv = (p - mu)*rstd*ln_g[c] + ln_b[c];
  Hout[m*C_+c] = fmaxf(hv, 0.f);
}

// ---------------------------------------------------------------------------
// Kernel 4: out = Ymean@Wo + bo + H@P2w + P2b. 8 rows/block.
// ---------------------------------------------------------------------------
__global__ void final_kernel(const float* __restrict__ Ymean,
                             const float* __restrict__ Hin,
                             const float* __restrict__ Wo, const float* __restrict__ bo,
                             const float* __restrict__ P2w, const float* __restrict__ P2b,
                             float* __restrict__ out) {
  __shared__ float ym[8][C_];
  __shared__ float hh[8][C_];
  const int r0 = blockIdx.x * 8;
  const int c  = threadIdx.x;
  #pragma unroll
  for (int r = 0; r < 8; ++r) {
    ym[r][c] = Ymean[(r0+r)*C_ + c];
    hh[r][c] = Hin[(r0+r)*C_ + c];
  }
  __syncthreads();
  float acc[8];
  #pragma unroll
  for (int r = 0; r < 8; ++r) acc[r] = bo[c] + P2b[c];
  for (int k = 0; k < C_; ++k) {
    float wo = Wo[k*C_ + c];
    float p2 = P2w[k*C_ + c];
    #pragma unroll
    for (int r = 0; r < 8; ++r)
      acc[r] = fmaf(ym[r][k], wo, fmaf(hh[r][k], p2, acc[r]));
  }
  #pragma unroll
  for (int r = 0; r < 8; ++r) out[(r0+r)*C_ + c] = acc[r];
}

// ---------------------------------------------------------------------------
extern "C" void kernel_launch(void* const* d_in, const int* in_sizes, int n_in,
                              void* d_out, int out_size, void* d_ws, size_t ws_size,
                              hipStream_t stream) {
  const float* fmap = (const float*)d_in[0];
  const float* kpts = (const float*)d_in[1];
  const float* meta = (const float*)d_in[2];
  const float* Wq   = (const float*)d_in[3];
  const float* bq   = (const float*)d_in[4];
  const float* Wk   = (const float*)d_in[5];
  const float* bk   = (const float*)d_in[6];
  const float* Wv   = (const float*)d_in[7];
  const float* bv   = (const float*)d_in[8];
  const float* Wo   = (const float*)d_in[9];
  const float* bo   = (const float*)d_in[10];
  const float* Wg   = (const float*)d_in[11];
  const float* bg   = (const float*)d_in[12];
  const float* P1w  = (const float*)d_in[13];
  const float* P1b  = (const float*)d_in[14];
  const float* ln_g = (const float*)d_in[15];
  const float* ln_b = (const float*)d_in[16];
  const float* P2w  = (const float*)d_in[17];
  const float* P2b  = (const float*)d_in[18];
  float* out = (float*)d_out;

  float* w = (float*)d_ws;
  float* kpt = w;  w += M_*C_;
  float* Qk  = w;  w += M_*C_;
  float* Kk  = w;  w += M_*C_;
  float* Vk  = w;  w += M_*C_;
  float* P1k = w;  w += M_*C_;
  float* Gk  = w;  w += M_*8;
  float* Qm  = w;  w += N_*C_;
  float* Km  = w;  w += N_*C_;
  float* Vm  = w;  w += N_*C_;
  float* P1m = w;  w += N_*C_;
  float* Gm  = w;  w += 32*8;
  float* Ym  = w;  w += M_*C_;
  float* Hh  = w;  w += M_*C_;

  gpool_kernel<<<M_, C_, 0, stream>>>(fmap, kpts, kpt);
  // meta rows (17): independent of gpool
  prep_kernel<<<(N_+7)/8, C_, 0, stream>>>(meta, N_,
      Wq,bq,Wk,bk,Wv,bv,Wg,bg, P1w + C_*C_, Qm,Km,Vm,Gm,P1m);
  // keypoint rows (544)
  prep_kernel<<<M_/8, C_, 0, stream>>>(kpt, M_,
      Wq,bq,Wk,bk,Wv,bv,Wg,bg, P1w, Qk,Kk,Vk,Gk,P1k);
  attn_ln_kernel<<<M_, C_, 0, stream>>>(Qk,Kk,Vk,Gk, Qm,Km,Vm,Gm,
      P1k,P1m,P1b, ln_g,ln_b, Ym,Hh);
  final_kernel<<<M_/8, C_, 0, stream>>>(Ym,Hh, Wo,bo, P2w,P2b, out);
}

// Round 9
// 379.514 us; speedup vs baseline: 1.4497x; 1.4497x over previous
//
#include <hip/hip_runtime.h>

#define B_ 32
#define N_ 17
#define C_ 256
#define H_ 96
#define W_ 72
#define M_ (B_*N_)        // 544
#define R_ (M_+N_)        // 561 unified rows: [kpt(544); meta(17)]

// ---------------------------------------------------------------------------
// Kernel 1: gaussian 5x5 pooling at keypoint locations.
// One block per (b,n) keypoint, one thread per channel. Scatter-bound.
// ---------------------------------------------------------------------------
__global__ void gpool_kernel(const float* __restrict__ fmap,
                             const float* __restrict__ kpts,
                             float* __restrict__ kpt_out) {
  const int m = blockIdx.x;          // b*17 + n
  const int b = m / N_;
  const int c = threadIdx.x;         // channel
  const float kx = kpts[m*2+0] * 0.25f;   // W/ORIG_W = 72/288
  const float ky = kpts[m*2+1] * 0.25f;   // H/ORIG_H = 96/384
  int xi = (int)kx; xi = min(max(xi, 2), W_-3);
  int yi = (int)ky; yi = min(max(yi, 2), H_-3);
  const float e1 = 0.8824969025845955f;   // exp(-1/8)
  const float e4 = 0.6065306597126334f;   // exp(-4/8)
  const float S  = 1.0f + 2.0f*e1 + 2.0f*e4;
  const float w1d[5] = { e4/S, e1/S, 1.0f/S, e1/S, e4/S };
  const float* base = fmap + ((size_t)(b*C_ + c)*H_ + (yi-2))*W_ + (xi-2);
  float acc = 0.f;
  #pragma unroll
  for (int dy = 0; dy < 5; ++dy) {
    const float* row = base + dy*W_;
    float rs = 0.f;
    #pragma unroll
    for (int dx = 0; dx < 5; ++dx) rs = fmaf(row[dx], w1d[dx], rs);
    acc = fmaf(rs, w1d[dy], acc);
  }
  kpt_out[m*C_ + c] = acc;
}

// ---------------------------------------------------------------------------
// Kernel 2: unified projections over 561 virtual rows [kpt; meta].
// grid = (71 rowblocks, 4 matrices). mtx: 0=Q 1=K 2=V 3=P1(+gate).
// Each block: stage 8 rows in LDS, one 256-k GEMM (k-unrolled x4).
// ---------------------------------------------------------------------------
__global__ void prep_kernel(const float* __restrict__ kpt,
                            const float* __restrict__ meta,
                            const float* __restrict__ Wq, const float* __restrict__ bq,
                            const float* __restrict__ Wk, const float* __restrict__ bk,
                            const float* __restrict__ Wv, const float* __restrict__ bv,
                            const float* __restrict__ P1w,
                            const float* __restrict__ Wg, const float* __restrict__ bg,
                            float* __restrict__ Q, float* __restrict__ K,
                            float* __restrict__ V, float* __restrict__ P1,
                            float* __restrict__ G) {
  __shared__ float xs[8][C_];
  __shared__ float gred[4][64];
  const int rb  = blockIdx.x;        // 0..70
  const int mtx = blockIdx.y;        // 0..3
  const int c   = threadIdx.x;
  const int r0  = rb * 8;
  const bool is_meta = (r0 >= M_);
  const int nvalid = is_meta ? (R_ - r0 < 8 ? R_ - r0 : 8) : 8;
  const float* X = is_meta ? (meta + (r0 - M_) * C_) : (kpt + (size_t)r0 * C_);
  #pragma unroll
  for (int r = 0; r < 8; ++r)
    xs[r][c] = (r < nvalid) ? X[r * C_ + c] : 0.f;
  __syncthreads();

  const float* Wp; const float* bp; float* op;
  if (mtx == 0)      { Wp = Wq; bp = bq; op = Q; }
  else if (mtx == 1) { Wp = Wk; bp = bk; op = K; }
  else if (mtx == 2) { Wp = Wv; bp = bv; op = V; }
  else { Wp = is_meta ? (P1w + C_*C_) : P1w; bp = nullptr; op = P1; }

  float acc[8];
  {
    const float bias = bp ? bp[c] : 0.f;
    #pragma unroll
    for (int r = 0; r < 8; ++r) acc[r] = bias;
  }
  for (int k = 0; k < C_; k += 4) {
    const float w0 = Wp[(k+0)*C_ + c];
    const float w1 = Wp[(k+1)*C_ + c];
    const float w2 = Wp[(k+2)*C_ + c];
    const float w3 = Wp[(k+3)*C_ + c];
    #pragma unroll
    for (int r = 0; r < 8; ++r) {
      float a = acc[r];
      a = fmaf(xs[r][k+0], w0, a);
      a = fmaf(xs[r][k+1], w1, a);
      a = fmaf(xs[r][k+2], w2, a);
      a = fmaf(xs[r][k+3], w3, a);
      acc[r] = a;
    }
  }
  #pragma unroll
  for (int r = 0; r < 8; ++r)
    if (r < nvalid) op[(size_t)(r0 + r) * C_ + c] = acc[r];

  // gate logits (mtx==3 blocks): 64 (row,head) combos x 4 k-quarters
  if (mtx == 3) {
    const int combo = c & 63;
    const int rr = combo >> 3, hh = combo & 7;
    const int qq = c >> 6;
    float p = 0.f;
    const int k0 = qq * 64;
    #pragma unroll 8
    for (int k = k0; k < k0 + 64; ++k)
      p = fmaf(xs[rr][k], Wg[k*8 + hh], p);
    gred[qq][combo] = p;
    __syncthreads();
    if (c < 64 && rr < nvalid)
      G[(r0 + rr)*8 + hh] = gred[0][c] + gred[1][c] + gred[2][c] + gred[3][c] + bg[hh];
  }
}

// ---------------------------------------------------------------------------
// Kernel 3: fused S=2 gated attention (mean over S) + LayerNorm/ReLU + final
// dual GEMV: out = Ymean@Wo + bo + H@P2w + P2b. 4 rows/block, 136 blocks.
// ---------------------------------------------------------------------------
__global__ void attn_final_kernel(
    const float* __restrict__ Q, const float* __restrict__ K,
    const float* __restrict__ V, const float* __restrict__ P1,
    const float* __restrict__ G,
    const float* __restrict__ P1b, const float* __restrict__ ln_g,
    const float* __restrict__ ln_b,
    const float* __restrict__ Wo, const float* __restrict__ bo,
    const float* __restrict__ P2w, const float* __restrict__ P2b,
    float* __restrict__ out) {
  __shared__ float ym[4][C_];
  __shared__ float hs[4][C_];
  __shared__ float red[4][8];
  const int c  = threadIdx.x;
  const int h  = c >> 5;
  const int m0 = blockIdx.x * 4;
  const float lg = ln_g[c], lb = ln_b[c], pb = P1b[c];

  for (int r = 0; r < 4; ++r) {
    const int m  = m0 + r;
    const int mm = M_ + (m % N_);          // unified meta row
    const float q0 = Q[(size_t)m*C_+c],  k0 = K[(size_t)m*C_+c],  v0 = V[(size_t)m*C_+c];
    const float q1 = Q[(size_t)mm*C_+c], k1 = K[(size_t)mm*C_+c], v1 = V[(size_t)mm*C_+c];
    float s00 = q0*k0, s01 = q0*k1, s10 = q1*k0, s11 = q1*k1;
    #pragma unroll
    for (int off = 16; off >= 1; off >>= 1) {   // stays inside 32-lane head
      s00 += __shfl_xor(s00, off);
      s01 += __shfl_xor(s01, off);
      s10 += __shfl_xor(s10, off);
      s11 += __shfl_xor(s11, off);
    }
    const float scale = 0.17677669529663687f;   // 1/sqrt(32)
    s00 *= scale; s01 *= scale; s10 *= scale; s11 *= scale;
    const float mx0 = fmaxf(s00, s01), mx1 = fmaxf(s10, s11);
    const float e00 = __expf(s00-mx0), e01 = __expf(s01-mx0);
    const float e10 = __expf(s10-mx1), e11 = __expf(s11-mx1);
    const float i0 = 1.f/(e00+e01), i1 = 1.f/(e10+e11);
    const float g0 = 1.f/(1.f + __expf(-G[m*8+h]));
    const float g1 = 1.f/(1.f + __expf(-G[mm*8+h]));
    const float y0 = (e00*v0 + e01*v1) * i0 * g0;
    const float y1 = (e10*v0 + e11*v1) * i1 * g1;
    ym[r][c] = 0.5f*(y0 + y1);

    // LayerNorm(P1[kpt] + P1[meta] + P1b) -> ReLU
    const float p = P1[(size_t)m*C_+c] + P1[(size_t)mm*C_+c] + pb;
    float s = p, s2 = p*p;
    #pragma unroll
    for (int off = 32; off >= 1; off >>= 1) {   // 64-lane wave reduce
      s  += __shfl_xor(s, off);
      s2 += __shfl_xor(s2, off);
    }
    const int wv = c >> 6;
    if ((c & 63) == 0) { red[r][wv*2] = s; red[r][wv*2+1] = s2; }
    __syncthreads();
    const float tot  = red[r][0]+red[r][2]+red[r][4]+red[r][6];
    const float tot2 = red[r][1]+red[r][3]+red[r][5]+red[r][7];
    const float mu   = tot * (1.f/256.f);
    const float var  = tot2 * (1.f/256.f) - mu*mu;
    const float rstd = rsqrtf(var + 1e-5f);
    hs[r][c] = fmaxf((p - mu)*rstd*lg + lb, 0.f);
  }
  __syncthreads();

  float acc[4];
  {
    const float b2 = bo[c] + P2b[c];
    #pragma unroll
    for (int r = 0; r < 4; ++r) acc[r] = b2;
  }
  for (int k = 0; k < C_; k += 4) {
    #pragma unroll
    for (int kk = 0; kk < 4; ++kk) {
      const float wo = Wo[(k+kk)*C_ + c];
      const float p2 = P2w[(k+kk)*C_ + c];
      #pragma unroll
      for (int r = 0; r < 4; ++r)
        acc[r] = fmaf(ym[r][k+kk], wo, fmaf(hs[r][k+kk], p2, acc[r]));
    }
  }
  #pragma unroll
  for (int r = 0; r < 4; ++r) out[(size_t)(m0 + r)*C_ + c] = acc[r];
}

// ---------------------------------------------------------------------------
extern "C" void kernel_launch(void* const* d_in, const int* in_sizes, int n_in,
                              void* d_out, int out_size, void* d_ws, size_t ws_size,
                              hipStream_t stream) {
  const float* fmap = (const float*)d_in[0];
  const float* kpts = (const float*)d_in[1];
  const float* meta = (const float*)d_in[2];
  const float* Wq   = (const float*)d_in[3];
  const float* bq   = (const float*)d_in[4];
  const float* Wk   = (const float*)d_in[5];
  const float* bk   = (const float*)d_in[6];
  const float* Wv   = (const float*)d_in[7];
  const float* bv   = (const float*)d_in[8];
  const float* Wo   = (const float*)d_in[9];
  const float* bo   = (const float*)d_in[10];
  const float* Wg   = (const float*)d_in[11];
  const float* bg   = (const float*)d_in[12];
  const float* P1w  = (const float*)d_in[13];
  const float* P1b  = (const float*)d_in[14];
  const float* ln_g = (const float*)d_in[15];
  const float* ln_b = (const float*)d_in[16];
  const float* P2w  = (const float*)d_in[17];
  const float* P2b  = (const float*)d_in[18];
  float* out = (float*)d_out;

  float* w = (float*)d_ws;
  float* kpt = w;  w += M_*C_;
  float* Qu  = w;  w += R_*C_;
  float* Ku  = w;  w += R_*C_;
  float* Vu  = w;  w += R_*C_;
  float* P1u = w;  w += R_*C_;
  float* Gu  = w;  w += R_*8;

  gpool_kernel<<<M_, C_, 0, stream>>>(fmap, kpts, kpt);
  prep_kernel<<<dim3(71, 4), C_, 0, stream>>>(kpt, meta,
      Wq,bq,Wk,bk,Wv,bv, P1w, Wg,bg, Qu,Ku,Vu,P1u,Gu);
  attn_final_kernel<<<M_/4, C_, 0, stream>>>(Qu,Ku,Vu,P1u,Gu,
      P1b, ln_g, ln_b, Wo, bo, P2w, P2b, out);
}

// Round 13
// 379.071 us; speedup vs baseline: 1.4513x; 1.0012x over previous
//
#include <hip/hip_runtime.h>

#define B_ 32
#define N_ 17
#define C_ 256
#define H_ 96
#define W_ 72
#define M_ (B_*N_)        // 544
#define R_ (M_+N_)        // 561 unified rows: [kpt(544); meta(17)]

// ---------------------------------------------------------------------------
// Kernel 1: gaussian 5x5 pooling at keypoint locations.
// One block per (b,n) keypoint, one thread per channel.
// v2: each 5-float row is covered by two 16B-aligned float4 loads
// (row base is 288B-aligned; a0=(xi-2)&~3 gives a0+8 <= W exactly).
// All 10 loads independent -> deep VMEM pipeline. `off` is block-uniform
// (same keypoint for the whole block) -> uniform branch, static indices.
// ---------------------------------------------------------------------------
__global__ void gpool_kernel(const float* __restrict__ fmap,
                             const float* __restrict__ kpts,
                             float* __restrict__ kpt_out) {
  const int m = blockIdx.x;          // b*17 + n
  const int b = m / N_;
  const int c = threadIdx.x;         // channel
  const float kx = kpts[m*2+0] * 0.25f;   // W/ORIG_W = 72/288
  const float ky = kpts[m*2+1] * 0.25f;   // H/ORIG_H = 96/384
  int xi = (int)kx; xi = min(max(xi, 2), W_-3);
  int yi = (int)ky; yi = min(max(yi, 2), H_-3);
  const int a0  = (xi - 2) & ~3;     // aligned float4 start, 0..64
  const int off = (xi - 2) - a0;     // 0..3, block-uniform

  const float e1 = 0.8824969025845955f;   // exp(-1/8)
  const float e4 = 0.6065306597126334f;   // exp(-4/8)
  const float S  = 1.0f + 2.0f*e1 + 2.0f*e4;
  const float w1d[5] = { e4/S, e1/S, 1.0f/S, e1/S, e4/S };

  const float* base = fmap + ((size_t)(b*C_ + c)*H_ + (yi-2))*W_ + a0;
  float4 lo[5], hi[5];
  #pragma unroll
  for (int dy = 0; dy < 5; ++dy) {
    lo[dy] = *(const float4*)(base + dy*W_);
    hi[dy] = *(const float4*)(base + dy*W_ + 4);
  }

  float acc = 0.f;
  #pragma unroll
  for (int o = 0; o < 4; ++o) {
    if (off == o) {                  // uniform across block
      #pragma unroll
      for (int dy = 0; dy < 5; ++dy) {
        const float v[8] = { lo[dy].x, lo[dy].y, lo[dy].z, lo[dy].w,
                             hi[dy].x, hi[dy].y, hi[dy].z, hi[dy].w };
        float rs = 0.f;
        #pragma unroll
        for (int dx = 0; dx < 5; ++dx)      // o+dx is compile-time constant
          rs = fmaf(v[o+dx], w1d[dx], rs);
        acc = fmaf(rs, w1d[dy], acc);
      }
    }
  }
  kpt_out[m*C_ + c] = acc;
}

// ---------------------------------------------------------------------------
// Kernel 2: unified projections over 561 virtual rows [kpt; meta].
// grid = (71 rowblocks, 4 matrices). mtx: 0=Q 1=K 2=V 3=P1(+gate).
// Each block: stage 8 rows in LDS, one 256-k GEMM (k-unrolled x4).
// ---------------------------------------------------------------------------
__global__ void prep_kernel(const float* __restrict__ kpt,
                            const float* __restrict__ meta,
                            const float* __restrict__ Wq, const float* __restrict__ bq,
                            const float* __restrict__ Wk, const float* __restrict__ bk,
                            const float* __restrict__ Wv, const float* __restrict__ bv,
                            const float* __restrict__ P1w,
                            const float* __restrict__ Wg, const float* __restrict__ bg,
                            float* __restrict__ Q, float* __restrict__ K,
                            float* __restrict__ V, float* __restrict__ P1,
                            float* __restrict__ G) {
  __shared__ float xs[8][C_];
  __shared__ float gred[4][64];
  const int rb  = blockIdx.x;        // 0..70
  const int mtx = blockIdx.y;        // 0..3
  const int c   = threadIdx.x;
  const int r0  = rb * 8;
  const bool is_meta = (r0 >= M_);
  const int nvalid = is_meta ? (R_ - r0 < 8 ? R_ - r0 : 8) : 8;
  const float* X = is_meta ? (meta + (r0 - M_) * C_) : (kpt + (size_t)r0 * C_);
  #pragma unroll
  for (int r = 0; r < 8; ++r)
    xs[r][c] = (r < nvalid) ? X[r * C_ + c] : 0.f;
  __syncthreads();

  const float* Wp; const float* bp; float* op;
  if (mtx == 0)      { Wp = Wq; bp = bq; op = Q; }
  else if (mtx == 1) { Wp = Wk; bp = bk; op = K; }
  else if (mtx == 2) { Wp = Wv; bp = bv; op = V; }
  else { Wp = is_meta ? (P1w + C_*C_) : P1w; bp = nullptr; op = P1; }

  float acc[8];
  {
    const float bias = bp ? bp[c] : 0.f;
    #pragma unroll
    for (int r = 0; r < 8; ++r) acc[r] = bias;
  }
  for (int k = 0; k < C_; k += 4) {
    const float w0 = Wp[(k+0)*C_ + c];
    const float w1 = Wp[(k+1)*C_ + c];
    const float w2 = Wp[(k+2)*C_ + c];
    const float w3 = Wp[(k+3)*C_ + c];
    #pragma unroll
    for (int r = 0; r < 8; ++r) {
      float a = acc[r];
      a = fmaf(xs[r][k+0], w0, a);
      a = fmaf(xs[r][k+1], w1, a);
      a = fmaf(xs[r][k+2], w2, a);
      a = fmaf(xs[r][k+3], w3, a);
      acc[r] = a;
    }
  }
  #pragma unroll
  for (int r = 0; r < 8; ++r)
    if (r < nvalid) op[(size_t)(r0 + r) * C_ + c] = acc[r];

  // gate logits (mtx==3 blocks): 64 (row,head) combos x 4 k-quarters
  if (mtx == 3) {
    const int combo = c & 63;
    const int rr = combo >> 3, hh = combo & 7;
    const int qq = c >> 6;
    float p = 0.f;
    const int k0 = qq * 64;
    #pragma unroll 8
    for (int k = k0; k < k0 + 64; ++k)
      p = fmaf(xs[rr][k], Wg[k*8 + hh], p);
    gred[qq][combo] = p;
    __syncthreads();
    if (c < 64 && rr < nvalid)
      G[(r0 + rr)*8 + hh] = gred[0][c] + gred[1][c] + gred[2][c] + gred[3][c] + bg[hh];
  }
}

// ---------------------------------------------------------------------------
// Kernel 3: fused S=2 gated attention (mean over S) + LayerNorm/ReLU + final
// dual GEMV: out = Ymean@Wo + bo + H@P2w + P2b. 4 rows/block, 136 blocks.
// ---------------------------------------------------------------------------
__global__ void attn_final_kernel(
    const float* __restrict__ Q, const float* __restrict__ K,
    const float* __restrict__ V, const float* __restrict__ P1,
    const float* __restrict__ G,
    const float* __restrict__ P1b, const float* __restrict__ ln_g,
    const float* __restrict__ ln_b,
    const float* __restrict__ Wo, const float* __restrict__ bo,
    const float* __restrict__ P2w, const float* __restrict__ P2b,
    float* __restrict__ out) {
  __shared__ float ym[4][C_];
  __shared__ float hs[4][C_];
  __shared__ float red[4][8];
  const int c  = threadIdx.x;
  const int h  = c >> 5;
  const int m0 = blockIdx.x * 4;
  const float lg = ln_g[c], lb = ln_b[c], pb = P1b[c];

  for (int r = 0; r < 4; ++r) {
    const int m  = m0 + r;
    const int mm = M_ + (m % N_);          // unified meta row
    const float q0 = Q[(size_t)m*C_+c],  k0 = K[(size_t)m*C_+c],  v0 = V[(size_t)m*C_+c];
    const float q1 = Q[(size_t)mm*C_+c], k1 = K[(size_t)mm*C_+c], v1 = V[(size_t)mm*C_+c];
    float s00 = q0*k0, s01 = q0*k1, s10 = q1*k0, s11 = q1*k1;
    #pragma unroll
    for (int off = 16; off >= 1; off >>= 1) {   // stays inside 32-lane head
      s00 += __shfl_xor(s00, off);
      s01 += __shfl_xor(s01, off);
      s10 += __shfl_xor(s10, off);
      s11 += __shfl_xor(s11, off);
    }
    const float scale = 0.17677669529663687f;   // 1/sqrt(32)
    s00 *= scale; s01 *= scale; s10 *= scale; s11 *= scale;
    const float mx0 = fmaxf(s00, s01), mx1 = fmaxf(s10, s11);
    const float e00 = __expf(s00-mx0), e01 = __expf(s01-mx0);
    const float e10 = __expf(s10-mx1), e11 = __expf(s11-mx1);
    const float i0 = 1.f/(e00+e01), i1 = 1.f/(e10+e11);
    const float g0 = 1.f/(1.f + __expf(-G[m*8+h]));
    const float g1 = 1.f/(1.f + __expf(-G[mm*8+h]));
    const float y0 = (e00*v0 + e01*v1) * i0 * g0;
    const float y1 = (e10*v0 + e11*v1) * i1 * g1;
    ym[r][c] = 0.5f*(y0 + y1);

    // LayerNorm(P1[kpt] + P1[meta] + P1b) -> ReLU
    const float p = P1[(size_t)m*C_+c] + P1[(size_t)mm*C_+c] + pb;
    float s = p, s2 = p*p;
    #pragma unroll
    for (int off = 32; off >= 1; off >>= 1) {   // 64-lane wave reduce
      s  += __shfl_xor(s, off);
      s2 += __shfl_xor(s2, off);
    }
    const int wv = c >> 6;
    if ((c & 63) == 0) { red[r][wv*2] = s; red[r][wv*2+1] = s2; }
    __syncthreads();
    const float tot  = red[r][0]+red[r][2]+red[r][4]+red[r][6];
    const float tot2 = red[r][1]+red[r][3]+red[r][5]+red[r][7];
    const float mu   = tot * (1.f/256.f);
    const float var  = tot2 * (1.f/256.f) - mu*mu;
    const float rstd = rsqrtf(var + 1e-5f);
    hs[r][c] = fmaxf((p - mu)*rstd*lg + lb, 0.f);
  }
  __syncthreads();

  float acc[4];
  {
    const float b2 = bo[c] + P2b[c];
    #pragma unroll
    for (int r = 0; r < 4; ++r) acc[r] = b2;
  }
  for (int k = 0; k < C_; k += 4) {
    #pragma unroll
    for (int kk = 0; kk < 4; ++kk) {
      const float wo = Wo[(k+kk)*C_ + c];
      const float p2 = P2w[(k+kk)*C_ + c];
      #pragma unroll
      for (int r = 0; r < 4; ++r)
        acc[r] = fmaf(ym[r][k+kk], wo, fmaf(hs[r][k+kk], p2, acc[r]));
    }
  }
  #pragma unroll
  for (int r = 0; r < 4; ++r) out[(size_t)(m0 + r)*C_ + c] = acc[r];
}

// ---------------------------------------------------------------------------
extern "C" void kernel_launch(void* const* d_in, const int* in_sizes, int n_in,
                              void* d_out, int out_size, void* d_ws, size_t ws_size,
                              hipStream_t stream) {
  const float* fmap = (const float*)d_in[0];
  const float* kpts = (const float*)d_in[1];
  const float* meta = (const float*)d_in[2];
  const float* Wq   = (const float*)d_in[3];
  const float* bq   = (const float*)d_in[4];
  const float* Wk   = (const float*)d_in[5];
  const float* bk   = (const float*)d_in[6];
  const float* Wv   = (const float*)d_in[7];
  const float* bv   = (const float*)d_in[8];
  const float* Wo   = (const float*)d_in[9];
  const float* bo   = (const float*)d_in[10];
  const float* Wg   = (const float*)d_in[11];
  const float* bg   = (const float*)d_in[12];
  const float* P1w  = (const float*)d_in[13];
  const float* P1b  = (const float*)d_in[14];
  const float* ln_g = (const float*)d_in[15];
  const float* ln_b = (const float*)d_in[16];
  const float* P2w  = (const float*)d_in[17];
  const float* P2b  = (const float*)d_in[18];
  float* out = (float*)d_out;

  float* w = (float*)d_ws;
  float* kpt = w;  w += M_*C_;
  float* Qu  = w;  w += R_*C_;
  float* Ku  = w;  w += R_*C_;
  float* Vu  = w;  w += R_*C_;
  float* P1u = w;  w += R_*C_;
  float* Gu  = w;  w += R_*8;

  gpool_kernel<<<M_, C_, 0, stream>>>(fmap, kpts, kpt);
  prep_kernel<<<dim3(71, 4), C_, 0, stream>>>(kpt, meta,
      Wq,bq,Wk,bk,Wv,bv, P1w, Wg,bg, Qu,Ku,Vu,P1u,Gu);
  attn_final_kernel<<<M_/4, C_, 0, stream>>>(Qu,Ku,Vu,P1u,Gu,
      P1b, ln_g, ln_b, Wo, bo, P2w, P2b, out);
}